// Round 2
// baseline (2532.978 us; speedup 1.0000x reference)
//
#include <hip/hip_runtime.h>

#define NEMB 1024
#define CDIM 256
#define NPOS 131072            // 32*64*64 positions
#define Z_ELEMS 33554432       // 32*256*64*64

// d_out is FLOAT32, flat layout [z_q | cl | cml | indices] (verified r0/r5).
#define SC_OFF  ((size_t)33554432)
#define IDX_OFF ((size_t)33554434)

typedef float f32x4 __attribute__((ext_vector_type(4)));

// Bitwise replication of numpy pairwise_sum of a[i]^2 over 256 floats with a
// stride: n=256 -> split 128+128; each 128-block uses 8 stride-8 accumulators
// combined ((r0+r1)+(r2+r3))+((r4+r5)+(r6+r7)). Squares are materialized
// (rounded) separately -> FP contraction OFF.
__device__ __forceinline__ float np_pairwise_sq256_s(const float* a, int stride) {
#pragma clang fp contract(off)
  float s0, s1;
  {
    float r[8];
#pragma unroll
    for (int j = 0; j < 8; ++j) { float v = a[j * stride]; r[j] = v * v; }
#pragma unroll
    for (int i = 8; i < 128; i += 8) {
#pragma unroll
      for (int j = 0; j < 8; ++j) { float v = a[(i + j) * stride]; r[j] += v * v; }
    }
    s0 = ((r[0] + r[1]) + (r[2] + r[3])) + ((r[4] + r[5]) + (r[6] + r[7]));
  }
  {
    float r[8];
#pragma unroll
    for (int j = 0; j < 8; ++j) { float v = a[(128 + j) * stride]; r[j] = v * v; }
#pragma unroll
    for (int i = 8; i < 128; i += 8) {
#pragma unroll
      for (int j = 0; j < 8; ++j) { float v = a[(128 + i + j) * stride]; r[j] += v * v; }
    }
    s1 = ((r[0] + r[1]) + (r[2] + r[3])) + ((r[4] + r[5]) + (r[6] + r[7]));
  }
  return s0 + s1;
}

__global__ void vq_bsq(const float* __restrict__ cb, float* __restrict__ Bsq,
                       double* __restrict__ loss_acc) {
  int k = blockIdx.x * blockDim.x + threadIdx.x;
  if (k == 0) *loss_acc = 0.0;
  if (k < NEMB) Bsq[k] = np_pairwise_sq256_s(cb + (size_t)k * CDIM, 1);
}

// lane k = tid = CODE index; acc[32] = one accumulator per position of the
// 32-position tile. z-tile (32KB) staged in LDS, read via wave-uniform
// ds_read_b128 broadcasts (conflict-free, DS pipe, off the scalar pipe that
// round-1 showed to be the stall). Codebook streams through per-lane VGPRs
// (double-buffered float4, immediate-offset loads). Per-(position,code) FMA
// chain: single accumulator, strictly ascending c -> bitwise identical to
// the verified kernel.
__global__ __launch_bounds__(1024, 4) void vq_main(
    const float* __restrict__ z, const float* __restrict__ cb,
    const float* __restrict__ Bsq, float* __restrict__ out,
    double* __restrict__ loss_acc) {
  __shared__ float zt[256][32];     // [c][p], 32KB
  __shared__ float A_lds[32];
  __shared__ float dmin_s[16][32];
  __shared__ int   kmin_s[16][32];
  __shared__ int   idx_s[32];
  __shared__ double wsum[16];

  const int tid = threadIdx.x;
  const int wv = tid >> 6;
  const int lane = tid & 63;
  const int bh2 = blockIdx.x;                      // (b*64 + h)*2 + half
  // zoff = b*CDIM*4096 + h*64 + half*32
  const int zoff = ((bh2 >> 7) << 20) | (((bh2 >> 1) & 63) << 6) | ((bh2 & 1) << 5);

  // ||z||^2 per position (np pairwise order, stride 4096), 32 lanes of wave 0.
  if (tid < 32) A_lds[tid] = np_pairwise_sq256_s(z + zoff + tid, 4096);

  // Stage z-tile: 2048 float4 quads; zt[c][q*4..q*4+3] = z[zoff + c*4096 + q*4].
  for (int i = tid; i < 2048; i += 1024) {
    const int c = i >> 3, q = i & 7;
    *(f32x4*)&zt[c][q * 4] = *(const f32x4*)(z + zoff + (c << 12) + (q << 2));
  }
  __syncthreads();

  float acc[32];
#pragma unroll
  for (int p = 0; p < 32; ++p) acc[p] = 0.0f;

  const f32x4* cbk4 = (const f32x4*)(cb + ((size_t)tid << 8));  // this code's row
  f32x4 e0 = cbk4[0];

  for (int c4 = 0; c4 < 64; ++c4) {
    const f32x4 e1 = cbk4[c4 + 1 < 64 ? c4 + 1 : 63];   // prefetch next 4 dims
    const int c = c4 << 2;
#pragma unroll
    for (int q = 0; q < 8; ++q) {
      // wave-uniform addresses -> ds_read_b128 broadcast, conflict-free
      const f32x4 z0 = *(const f32x4*)&zt[c + 0][q * 4];
      const f32x4 z1 = *(const f32x4*)&zt[c + 1][q * 4];
      const f32x4 z2 = *(const f32x4*)&zt[c + 2][q * 4];
      const f32x4 z3 = *(const f32x4*)&zt[c + 3][q * 4];
#pragma unroll
      for (int i = 0; i < 4; ++i) {
        float a = acc[q * 4 + i];
        a = __builtin_fmaf(z0[i], e0.x, a);
        a = __builtin_fmaf(z1[i], e0.y, a);
        a = __builtin_fmaf(z2[i], e0.z, a);
        a = __builtin_fmaf(z3[i], e0.w, a);
        acc[q * 4 + i] = a;
      }
    }
    e0 = e1;
  }

  // d = fl(fl(A+B) - 2*C) exactly as the verified kernel. Argmin over codes =
  // lexicographic (d, k) butterfly across lanes (lane order == k order),
  // then ascending-wave reduce -> numpy first-index tie semantics.
  const float Bk = Bsq[tid];
#pragma unroll
  for (int p = 0; p < 32; ++p) {
    float dm = (A_lds[p] + Bk) - 2.0f * acc[p];
    int km = tid;
#pragma unroll
    for (int m = 32; m; m >>= 1) {
      float d2 = __shfl_xor(dm, m);
      int k2 = __shfl_xor(km, m);
      if (d2 < dm || (d2 == dm && k2 < km)) { dm = d2; km = k2; }
    }
    if (lane == 0) { dmin_s[wv][p] = dm; kmin_s[wv][p] = km; }
  }
  __syncthreads();

  if (tid < 32) {
    float dm = dmin_s[0][tid];
    int km = kmin_s[0][tid];
#pragma unroll
    for (int v = 1; v < 16; ++v) {   // ascending wave = ascending k chunks
      float dv = dmin_s[v][tid];
      int kv = kmin_s[v][tid];
      if (dv < dm) { dm = dv; km = kv; }  // strict < : first-index ties
    }
    idx_s[tid] = km;
    out[IDX_OFF + (size_t)bh2 * 32 + tid] = (float)km;   // fp32 index
  }
  __syncthreads();

  // z_q = fl(z + fl(e - z)) fp32 (z from LDS: identical bits); loss in double.
  double lsum = 0.0;
#pragma unroll
  for (int i = tid; i < 256 * 32; i += 1024) {
    const int p = i & 31, c = i >> 5;
    const float e = cb[((size_t)idx_s[p] << 8) + c];
    const float zz = zt[c][p];
    const float diff = e - zz;
    lsum += (double)diff * (double)diff;
    out[zoff + (c << 12) + p] = zz + diff;
  }
  for (int off = 32; off; off >>= 1) lsum += __shfl_down(lsum, off);
  if (lane == 0) wsum[wv] = lsum;
  __syncthreads();
  if (tid == 0) {
    double t = 0.0;
#pragma unroll
    for (int v = 0; v < 16; ++v) t += wsum[v];
    atomicAdd(loss_acc, t);
  }
}

__global__ void vq_finalize(const double* __restrict__ loss_acc,
                            float* __restrict__ out) {
  double m = *loss_acc / (double)Z_ELEMS;
  out[SC_OFF] = (float)m;
  out[SC_OFF + 1] = (float)(0.25 * m);
}

extern "C" void kernel_launch(void* const* d_in, const int* in_sizes, int n_in,
                              void* d_out, int out_size, void* d_ws,
                              size_t ws_size, hipStream_t stream) {
  (void)n_in; (void)ws_size; (void)out_size;
  const float* z;
  const float* cb;
  if (in_sizes[0] == Z_ELEMS) {
    z = (const float*)d_in[0];
    cb = (const float*)d_in[1];
  } else {
    z = (const float*)d_in[1];
    cb = (const float*)d_in[0];
  }
  float* out = (float*)d_out;
  double* loss = (double*)d_ws;                 // 8 bytes
  float* Bsq = (float*)((char*)d_ws + 256);     // 4 KB

  vq_bsq<<<dim3(16), dim3(64), 0, stream>>>(cb, Bsq, loss);
  vq_main<<<dim3(4096), dim3(1024), 0, stream>>>(z, cb, Bsq, out, loss);
  vq_finalize<<<dim3(1), dim3(1), 0, stream>>>(loss, out);
}

// Round 3
// 587.157 us; speedup vs baseline: 4.3140x; 4.3140x over previous
//
#include <hip/hip_runtime.h>

#define NEMB 1024
#define CDIM 256
#define NPOS 131072            // 32*64*64 positions
#define Z_ELEMS 33554432       // 32*256*64*64

// d_out is FLOAT32, flat layout [z_q | cl | cml | indices] (verified r0/r5).
#define SC_OFF  ((size_t)33554432)
#define IDX_OFF ((size_t)33554434)

#define CAP 320                 // candidate list cap per wave (E~90, >10 sigma)
#define EPS 3.0e-3f             // >= certified |key - (d_ref - A)| bound (~1.5e-3)
#define NEG2S (-1.953125e-3f)   // -2 * 2^-10... = -2/1024 = -2^-9, exact pow2

typedef _Float16 half8 __attribute__((ext_vector_type(8)));
typedef float f32x4 __attribute__((ext_vector_type(4)));

// Bitwise replication of numpy pairwise_sum of a[i]^2 over 256 floats with a
// stride: n=256 -> split 128+128; each 128-block uses 8 stride-8 accumulators
// combined ((r0+r1)+(r2+r3))+((r4+r5)+(r6+r7)). FP contraction OFF.
__device__ __forceinline__ float np_pairwise_sq256_s(const float* a, int stride) {
#pragma clang fp contract(off)
  float s0, s1;
  {
    float r[8];
#pragma unroll
    for (int j = 0; j < 8; ++j) { float v = a[j * stride]; r[j] = v * v; }
#pragma unroll
    for (int i = 8; i < 128; i += 8) {
#pragma unroll
      for (int j = 0; j < 8; ++j) { float v = a[(i + j) * stride]; r[j] += v * v; }
    }
    s0 = ((r[0] + r[1]) + (r[2] + r[3])) + ((r[4] + r[5]) + (r[6] + r[7]));
  }
  {
    float r[8];
#pragma unroll
    for (int j = 0; j < 8; ++j) { float v = a[(128 + j) * stride]; r[j] = v * v; }
#pragma unroll
    for (int i = 8; i < 128; i += 8) {
#pragma unroll
      for (int j = 0; j < 8; ++j) { float v = a[(128 + i + j) * stride]; r[j] += v * v; }
    }
    s1 = ((r[0] + r[1]) + (r[2] + r[3])) + ((r[4] + r[5]) + (r[6] + r[7]));
  }
  return s0 + s1;
}

// Prep: Bsq (exact np pairwise) + codebook -> fp16 scaled by 2^10 (exact pow2
// scale in fp32, then RNE fp16 convert; kills fp16 subnormals since |e|<=2^-10).
__global__ void vq_prep(const float* __restrict__ cb, float* __restrict__ Bsq,
                        _Float16* __restrict__ cb16, double* __restrict__ loss_acc) {
  const int k = blockIdx.x, lane = threadIdx.x;
  if (k == 0 && lane == 0) *loss_acc = 0.0;
  if (lane == 0) Bsq[k] = np_pairwise_sq256_s(cb + (size_t)k * CDIM, 1);
  const float* row = cb + (size_t)k * CDIM;
#pragma unroll
  for (int i = 0; i < 4; ++i) {
    int c = (lane << 2) + i;
    cb16[((size_t)k << 8) + c] = (_Float16)(row[c] * 1024.0f);
  }
}

#define LOADB(buf, t) do {                                                     \
    const _Float16* bp_ = cb16 + ((((t) << 4) + col) << 8) + (krow << 3);      \
    _Pragma("unroll")                                                          \
    for (int ks_ = 0; ks_ < 8; ++ks_) (buf)[ks_] = *(const half8*)(bp_ + (ks_ << 5)); \
  } while (0)

#define TILE_CORE(buf)                                                         \
  f32x4 ac0 = {0.f, 0.f, 0.f, 0.f}, ac1 = ac0, ac2 = ac0, ac3 = ac0;           \
  _Pragma("unroll")                                                            \
  for (int ks_ = 0; ks_ < 8; ++ks_) {                                          \
    ac0 = __builtin_amdgcn_mfma_f32_16x16x32_f16(a[0][ks_], (buf)[ks_], ac0, 0, 0, 0); \
    ac1 = __builtin_amdgcn_mfma_f32_16x16x32_f16(a[1][ks_], (buf)[ks_], ac1, 0, 0, 0); \
    ac2 = __builtin_amdgcn_mfma_f32_16x16x32_f16(a[2][ks_], (buf)[ks_], ac2, 0, 0, 0); \
    ac3 = __builtin_amdgcn_mfma_f32_16x16x32_f16(a[3][ks_], (buf)[ks_], ac3, 0, 0, 0); \
  }

#define TILE1(buf, t) do {                                                     \
    const float Bk = Bs[((t) << 4) + col];                                     \
    TILE_CORE(buf)                                                             \
    _Pragma("unroll") for (int r_ = 0; r_ < 4; ++r_) {                         \
      mv[0][r_] = fminf(mv[0][r_], __builtin_fmaf(NEG2S, ac0[r_], Bk));        \
      mv[1][r_] = fminf(mv[1][r_], __builtin_fmaf(NEG2S, ac1[r_], Bk));        \
      mv[2][r_] = fminf(mv[2][r_], __builtin_fmaf(NEG2S, ac2[r_], Bk));        \
      mv[3][r_] = fminf(mv[3][r_], __builtin_fmaf(NEG2S, ac3[r_], Bk));        \
    }                                                                          \
  } while (0)

#define P2ONE(accv, m, t)                                                      \
  _Pragma("unroll") for (int r_ = 0; r_ < 4; ++r_) {                           \
    float key_ = __builtin_fmaf(NEG2S, (accv)[r_], Bk);                        \
    if (key_ <= mv[m][r_]) {                                                   \
      int s_ = atomicAdd(&candn[wv], 1);                                       \
      if (s_ < CAP) { candp[wv][s_] = (m << 4) + (krow << 2) + r_;             \
                      candk[wv][s_] = ((t) << 4) + col; }                      \
    }                                                                          \
  }

#define TILE2(buf, t) do {                                                     \
    const float Bk = Bs[((t) << 4) + col];                                     \
    TILE_CORE(buf)                                                             \
    P2ONE(ac0, 0, t) P2ONE(ac1, 1, t) P2ONE(ac2, 2, t) P2ONE(ac3, 3, t)        \
  } while (0)

// Wave = one (b,h) row = 64 positions; block = 4 waves. Phase 1: fp16 MFMA
// computes approx keys (B - 2*C~) for all 1024 codes, tracks per-position min.
// Phase 2: same MFMA recompute flags candidates key <= min + EPS (guaranteed
// to contain the exact argmin incl. all exact ties). Exact fp32 np-chain
// re-evaluation of candidates picks the bitwise-correct index.
__global__ __launch_bounds__(256) __attribute__((amdgpu_waves_per_eu(2, 2)))
void vq_main(const float* __restrict__ z, const float* __restrict__ cb,
             const _Float16* __restrict__ cb16, const float* __restrict__ Bsq,
             float* __restrict__ out, double* __restrict__ loss_acc) {
  __shared__ float A_lds[4][64];
  __shared__ float Bs[NEMB];
  __shared__ int   candp[4][CAP];
  __shared__ int   candk[4][CAP];
  __shared__ float candd[4][CAP];
  __shared__ int   candn[4];

  const int tid = threadIdx.x;
  const int wv = tid >> 6, lane = tid & 63;
  const int bh = (blockIdx.x << 2) | wv;
  const int zoff = ((bh >> 6) << 20) | ((bh & 63) << 6);   // b*CDIM*4096 + h*64
  const int col = lane & 15;     // A-row / B-col / D-col sub-index
  const int krow = lane >> 4;    // k-group 0..3

  for (int i = tid; i < NEMB; i += 256) Bs[i] = Bsq[i];
  A_lds[wv][lane] = np_pairwise_sq256_s(z + zoff + lane, 4096);  // ||z||^2, np order
  if (lane == 0) candn[wv] = 0;
  __syncthreads();

  // a_frags resident: a[m][ks] elem j = fp16(z[c = ks*32+krow*8+j][w = m*16+col])
  half8 a[4][8];
#pragma unroll
  for (int m = 0; m < 4; ++m)
#pragma unroll
    for (int ks = 0; ks < 8; ++ks)
#pragma unroll
      for (int j = 0; j < 8; ++j) {
        float v = z[zoff + ((ks * 32 + krow * 8 + j) << 12) + (m * 16 + col)];
        a[m][ks][j] = (_Float16)v;
      }

  // ---- Phase 1: min key per position ----
  float mv[4][4];
#pragma unroll
  for (int m = 0; m < 4; ++m)
#pragma unroll
    for (int r = 0; r < 4; ++r) mv[m][r] = INFINITY;

  half8 b0[8], b1[8];
  LOADB(b0, 0);
  for (int t = 0; t < 64; t += 2) {
    LOADB(b1, t + 1);
    TILE1(b0, t);
    if (t + 2 < 64) LOADB(b0, t + 2);
    TILE1(b1, t + 1);
  }

  // Reduce min across the 16 lanes (same krow group) holding different codes
  // for the same positions; then thr = min + EPS, kept in-register.
#pragma unroll
  for (int m = 0; m < 4; ++m)
#pragma unroll
    for (int r = 0; r < 4; ++r) {
      float v = mv[m][r];
      v = fminf(v, __shfl_xor(v, 1));
      v = fminf(v, __shfl_xor(v, 2));
      v = fminf(v, __shfl_xor(v, 4));
      v = fminf(v, __shfl_xor(v, 8));
      mv[m][r] = v + EPS;
    }

  // ---- Phase 2: recompute (bitwise-same) keys, collect candidates ----
  LOADB(b0, 0);
  for (int t = 0; t < 64; t += 2) {
    LOADB(b1, t + 1);
    TILE2(b0, t);
    if (t + 2 < 64) LOADB(b0, t + 2);
    TILE2(b1, t + 1);
  }

  // ---- Exact np-chain evaluation of candidates (lane-parallel) ----
  int n = candn[wv];
  if (n > CAP) n = CAP;
  for (int base = 0; base < n; base += 64) {
    int i = base + lane;
    if (i < n) {
      const int w = candp[wv][i], k = candk[wv][i];
      const float* zp = z + zoff + w;
      const float* ep = cb + ((size_t)k << 8);
      float acc = 0.0f;                     // BLAS chain: sequential ascending c
#pragma unroll 8
      for (int c = 0; c < CDIM; ++c)
        acc = __builtin_fmaf(zp[(size_t)c << 12], ep[c], acc);
      float tt = A_lds[wv][w] + Bs[k];      // fl(A+B)
      candd[wv][i] = __builtin_fmaf(-2.0f, acc, tt);  // fl(t - 2C), single rounding
    }
  }

  // Final per-position selection: lexicographic (d, k) = np first-index ties.
  float bd = INFINITY; int bk = 0;
  for (int i = 0; i < n; ++i) {
    if (candp[wv][i] == lane) {
      float d = candd[wv][i]; int k = candk[wv][i];
      if (d < bd || (d == bd && k < bk)) { bd = d; bk = k; }
    }
  }
  out[IDX_OFF + (size_t)bh * 64 + lane] = (float)bk;   // fp32 index

  // ---- Epilogue: z_q = fl(z + fl(e - z)); loss = sum (e-z)^2 in double ----
  double lsum = 0.0;
  const float* erow = cb + ((size_t)bk << 8);
  for (int c = 0; c < CDIM; ++c) {
    const float zz = z[zoff + (c << 12) + lane];
    const float diff = erow[c] - zz;
    lsum += (double)diff * (double)diff;
    out[zoff + (c << 12) + lane] = zz + diff;
  }
  for (int off = 32; off; off >>= 1) lsum += __shfl_down(lsum, off);
  if (lane == 0) atomicAdd(loss_acc, lsum);
}

__global__ void vq_finalize(const double* __restrict__ loss_acc,
                            float* __restrict__ out) {
  double m = *loss_acc / (double)Z_ELEMS;
  out[SC_OFF] = (float)m;
  out[SC_OFF + 1] = (float)(0.25 * m);
}

extern "C" void kernel_launch(void* const* d_in, const int* in_sizes, int n_in,
                              void* d_out, int out_size, void* d_ws,
                              size_t ws_size, hipStream_t stream) {
  (void)n_in; (void)ws_size; (void)out_size;
  const float* z;
  const float* cb;
  if (in_sizes[0] == Z_ELEMS) {
    z = (const float*)d_in[0];
    cb = (const float*)d_in[1];
  } else {
    z = (const float*)d_in[1];
    cb = (const float*)d_in[0];
  }
  float* out = (float*)d_out;
  double* loss = (double*)d_ws;                       // 8 B
  float* Bsq = (float*)((char*)d_ws + 256);           // 4 KB
  _Float16* cb16 = (_Float16*)((char*)d_ws + 8192);   // 512 KB (ws >= 520.2 KB)

  vq_prep<<<dim3(NEMB), dim3(64), 0, stream>>>(cb, Bsq, cb16, loss);
  vq_main<<<dim3(512), dim3(256), 0, stream>>>(z, cb, cb16, Bsq, out, loss);
  vq_finalize<<<dim3(1), dim3(1), 0, stream>>>(loss, out);
}